// Round 9
// baseline (503.291 us; speedup 1.0000x reference)
//
#include <hip/hip_runtime.h>

// AssociationLayer: masked Sinkhorn (100 iters) + mutual-argmax assignment.
// R14 = R13 with dir2 (K^T@u) moved from MFMA to VALU fma.
//  R13 post-mortem (255 us): loop is LDS-ISSUE bound: 384 ds_read_b128/CU/iter
//  (VF 8 + UF 8 + KTL 8 per wave x16) x ~8-12 cyc ~= the measured 4800
//  cyc/iter. MFMA B-operand broadcasts move 1024B/instr for 64B of distinct
//  data, and the matvec wastes 15/16 of each MFMA (identical B columns).
//  R14 dir2: lane owns 2 cols x 32 rows; K^T pair-packed bf16 in LDS
//  lane-linear (KCL, stride-1 b128, 0 conflicts, R12-proven); u read as
//  pairs (4 b128 vs 8); compute = 16 pairs x (unpack shl/and + 4 fma) on the
//  idle VALU; reduce over rc lanes = 2 free DPP xor + 1 swizzle xor4.
//  LDS/wave/iter: 24 -> 20 b128-class (kills KTL stream + 4 UF reads).
//  dir1 (MFMA + KA regs) and interior epilogue unchanged from R13.
//  Identical (u*k)*v mul order + identical bf16 K bits on both panels ->
//  bitwise-consistent mutual argmax. absmax ~1.0 (tie flips) vs thr 4.92.

#define T_MAX   256
#define L_FLAT  (257 * 257)
#define N_ITERS 100
#define LAMBDA_F 10.0f
#define EPS_F    1e-12f

#define QX1   0xB1     // quad_perm xor1 (DPP, free)
#define QX2   0x4E     // quad_perm xor2 (DPP, free)
#define SWZ4  0x101F   // ds_swizzle xor4
#define SWZ8  0x201F   // ds_swizzle xor8
#define SWZ16 0x401F   // ds_swizzle xor16

typedef short bf8   __attribute__((ext_vector_type(8)));  // 8 bf16 = 4 VGPRs
typedef float f32x4 __attribute__((ext_vector_type(4)));
typedef unsigned int u32x4 __attribute__((ext_vector_type(4)));

struct F4 { float a, b, c, d; };   // 16B payload, 4B-aligned packed store

template<int CTRL>
__device__ __forceinline__ float dpp_addf(float x) {
    int t = __builtin_amdgcn_update_dpp(0, __float_as_int(x), CTRL, 0xF, 0xF, true);
    return x + __int_as_float(t);
}
template<int CTRL>
__device__ __forceinline__ float dpp_maxf(float x) {
    int t = __builtin_amdgcn_update_dpp(0, __float_as_int(x), CTRL, 0xF, 0xF, true);
    return fmaxf(x, __int_as_float(t));
}
template<int CTRL>
__device__ __forceinline__ int dpp_ori(int x) {
    int t = __builtin_amdgcn_update_dpp(0, x, CTRL, 0xF, 0xF, true);
    return x | t;
}
template<int OFF>
__device__ __forceinline__ float swz_addf(float x) {
    return x + __int_as_float(__builtin_amdgcn_ds_swizzle(__float_as_int(x), OFF));
}
template<int OFF>
__device__ __forceinline__ float swz_maxf(float x) {
    return fmaxf(x, __int_as_float(__builtin_amdgcn_ds_swizzle(__float_as_int(x), OFF)));
}
template<int OFF>
__device__ __forceinline__ int swz_ori(int x) {
    return x | __builtin_amdgcn_ds_swizzle(x, OFF);
}
__device__ __forceinline__ float fast_rcp(float x) {
#if __has_builtin(__builtin_amdgcn_rcpf)
    return __builtin_amdgcn_rcpf(x);
#else
    return 1.0f / x;
#endif
}
__device__ __forceinline__ unsigned short f2bf(float x) {   // RNE f32->bf16
    unsigned u = __float_as_uint(x);
    return (unsigned short)((u + 0x7FFFu + ((u >> 16) & 1u)) >> 16);
}
__device__ __forceinline__ float bf2f(short s) {            // exact bf16->f32
    return __uint_as_float(((unsigned)(unsigned short)s) << 16);
}
__device__ __forceinline__ float bflo(unsigned u) {         // low bf16 of pair
    return __uint_as_float(u << 16);
}
__device__ __forceinline__ float bfhi(unsigned u) {         // high bf16 of pair
    return __uint_as_float(u & 0xFFFF0000u);
}

__global__ __launch_bounds__(1024, 1) void assoc_sinkhorn_kernel(
    const float* __restrict__ aff,
    const int*   __restrict__ ndet,
    const int*   __restrict__ ntrk,
    float*       __restrict__ out_t,
    float*       __restrict__ out_a)
{
    const int b   = blockIdx.x;
    const int nd  = ndet[b];
    const int nt  = ntrk[b];
    const int tid = threadIdx.x;
    const int w   = tid >> 6;     // wave 0..15 -> rows/cols 16w..16w+15
    const int l   = tid & 63;
    const int lr  = l & 15;       // dir1: m index within 16x16 tile
    const int lk  = l >> 4;       // dir1: k-group 0..3
    const int cp  = l >> 3;       // dir2: col-pair 0..7
    const int rc  = l & 7;        // dir2: row-chunk 0..7 (rows 32rc..32rc+31)

    // K^T pair-linear: [w][j(2)][g(4)][lane][4 uints=4 bf16-pairs] = 128 KB
    __shared__ __align__(16) unsigned KCL[16 * 8 * 64 * 4];
    __shared__ __align__(16) unsigned short u_bf[256];
    __shared__ __align__(16) unsigned short v_bf[256];
    __shared__ __align__(16) float u_f[256];
    __shared__ __align__(16) float v_f[256];
    __shared__ __align__(16) float SuAcc[2];   // ping-pong cross-wave sums
    __shared__ __align__(16) float SvAcc[2];
    __shared__ __align__(16) float rm_s[256];
    __shared__ __align__(16) float cm_s[256];

    const float ndf = (float)nd;
    const float ntf = (float)nt;

    // ---------------- prologue: build bf16 K fragments ----------------
    bf8 KA[8];   // row-panel (A-op): row 16w+lr, cols 32t+8lk+j
    const float* Ab = aff + (size_t)b * (T_MAX * T_MAX);

    const int myrow = 16 * w + lr;
    const int c0    = 16 * w + 2 * cp;           // dir2 col pair base
    unsigned* myKC0 = &KCL[((w * 8 + 0) * 64 + l) * 4];   // j=0, +g*256
    unsigned* myKC1 = &KCL[((w * 8 + 4) * 64 + l) * 4];   // j=1, +g*256

    {
        const bool rv = (myrow < nt);
        const float* rp = Ab + (size_t)myrow * T_MAX;
        #pragma unroll
        for (int t = 0; t < 8; ++t) {
            const int cc0 = 32 * t + 8 * lk;
            const float4 x0 = *reinterpret_cast<const float4*>(rp + cc0);
            const float4 x1 = *reinterpret_cast<const float4*>(rp + cc0 + 4);
            const float e[8] = {x0.x, x0.y, x0.z, x0.w, x1.x, x1.y, x1.z, x1.w};
            bf8 kk;
            #pragma unroll
            for (int j = 0; j < 8; ++j) {
                const float val = (rv && (cc0 + j) < nd) ? __expf(LAMBDA_F * e[j]) : 0.0f;
                kk[j] = (short)f2bf(val);
            }
            KA[t] = kk;
        }
    }
    {
        // col-panel: cols c0,c0+1; rows 32rc+2p,+1 packed as bf16 pairs
        #pragma unroll
        for (int j = 0; j < 2; ++j) {
            const int col = c0 + j;
            const bool cv = (col < nd);
            unsigned* dst = (j == 0) ? myKC0 : myKC1;
            #pragma unroll
            for (int g = 0; g < 4; ++g) {
                u32x4 pk;
                #pragma unroll
                for (int s = 0; s < 4; ++s) {
                    const int r = 32 * rc + 8 * g + 2 * s;
                    const float x0 = Ab[(size_t)r * T_MAX + col];
                    const float x1 = Ab[(size_t)(r + 1) * T_MAX + col];
                    const float f0 = (cv && r     < nt) ? __expf(LAMBDA_F * x0) : 0.0f;
                    const float f1 = (cv && r + 1 < nt) ? __expf(LAMBDA_F * x1) : 0.0f;
                    pk[s] = (unsigned)f2bf(f0) | ((unsigned)f2bf(f1) << 16);
                }
                *reinterpret_cast<u32x4*>(dst + g * 256) = pk;
            }
        }
    }

    if (tid < 256) v_bf[tid] = (tid < nd) ? f2bf(1.0f) : (unsigned short)0;
    if (tid == 0) {
        SuAcc[0] = 0.0f; SuAcc[1] = 0.0f;
        SvAcc[0] = ndf;  SvAcc[1] = 0.0f;   // initial Sv = nd (v=1 on valid cols)
    }
    __syncthreads();

    float vbd = 1.0f;   // v[nd]
    float ubd = 0.0f;   // u[nt]

    const int r_a0 = 16 * w + 4 * lk;   // base row of this lane's acc quad
    float u4[4] = {0.f, 0.f, 0.f, 0.f};
    float v0 = 0.0f, v1 = 0.0f;

    // loop-invariant validity masks
    float rvm[4];
    #pragma unroll
    for (int q = 0; q < 4; ++q) rvm[q] = ((r_a0 + q) < nt) ? 1.0f : 0.0f;
    const float cvm0 = (c0     < nd) ? 1.0f : 0.0f;
    const float cvm1 = (c0 + 1 < nd) ? 1.0f : 0.0f;

    // ---------------- Sinkhorn iterations ----------------
    for (int it = 0; it < N_ITERS; ++it) {
        const int p = it & 1;
        const float Sv = SvAcc[p];

        // ---- dir1: K @ v (MFMA, KA regs; VF = broadcast of v) ----
        f32x4 acc = {0.0f, 0.0f, 0.0f, 0.0f};
        #pragma unroll
        for (int t = 0; t < 8; ++t) {
            const bf8 VF = *reinterpret_cast<const bf8*>(&v_bf[32 * t + 8 * lk]);
            acc = __builtin_amdgcn_mfma_f32_16x16x32_bf16(KA[t], VF, acc, 0, 0, 0);
        }

        const float vbdE = vbd + EPS_F;
        #pragma unroll
        for (int q = 0; q < 4; ++q)
            u4[q] = rvm[q] * fast_rcp(acc[q] + vbdE);

        // wave Sigma(u): fold lk groups (x16, x32), one atomic
        {
            float su = (u4[0] + u4[1]) + (u4[2] + u4[3]);
            su = swz_addf<SWZ16>(su);
            su += __shfl_xor(su, 32, 64);
            if (l == 0) atomicAdd(&SuAcc[p], su);
        }
        if (tid == 0) SuAcc[p ^ 1] = 0.0f;   // stale slot: last read prev iter

        // publish u as bf16; writers: lr==0 lanes (4 rows each)
        if (lr == 0) {
            const unsigned p01 = (unsigned)f2bf(u4[0]) | ((unsigned)f2bf(u4[1]) << 16);
            const unsigned p23 = (unsigned)f2bf(u4[2]) | ((unsigned)f2bf(u4[3]) << 16);
            *reinterpret_cast<uint2*>(&u_bf[r_a0]) = uint2{p01, p23};
        }
        __syncthreads();   // barrier A: u + SuAcc[p] published

        const float Su = SuAcc[p];
        const float ubd_new = ndf * fast_rcp(Sv + vbd + EPS_F);
        const float vbd_new = ntf * fast_rcp(Su + ubd_new + EPS_F);

        // ---- dir2: K^T @ u (VALU fma; KCL pair-linear, u as pairs) ----
        const float ubdE = ubd_new + EPS_F;
        float t0 = 0.0f, t1 = 0.0f;
        {
            const u32x4* ub = reinterpret_cast<const u32x4*>(&u_bf[32 * rc]);
            #pragma unroll
            for (int g = 0; g < 4; ++g) {
                const u32x4 U  = ub[g];
                const u32x4 K0 = *reinterpret_cast<const u32x4*>(myKC0 + g * 256);
                const u32x4 K1 = *reinterpret_cast<const u32x4*>(myKC1 + g * 256);
                #pragma unroll
                for (int s = 0; s < 4; ++s) {
                    const float ulo = bflo(U[s]);
                    const float uhi = bfhi(U[s]);
                    t0 = fmaf(bflo(K0[s]), ulo, t0);
                    t0 = fmaf(bfhi(K0[s]), uhi, t0);
                    t1 = fmaf(bflo(K1[s]), ulo, t1);
                    t1 = fmaf(bfhi(K1[s]), uhi, t1);
                }
            }
        }
        // reduce over rc lanes {l^1, l^2, l^4}: 2 free DPP + 1 swizzle
        t0 = dpp_addf<QX1>(t0); t0 = dpp_addf<QX2>(t0); t0 = swz_addf<SWZ4>(t0);
        t1 = dpp_addf<QX1>(t1); t1 = dpp_addf<QX2>(t1); t1 = swz_addf<SWZ4>(t1);

        v0 = cvm0 * fast_rcp(t0 + ubdE);
        v1 = cvm1 * fast_rcp(t1 + ubdE);

        // wave Sigma(v): varies over cp (stride 8): xor8, xor16, xor32
        {
            float sv = v0 + v1;
            sv = swz_addf<SWZ8>(sv);
            sv = swz_addf<SWZ16>(sv);
            sv += __shfl_xor(sv, 32, 64);
            if (l == 0) atomicAdd(&SvAcc[p ^ 1], sv);
        }
        if (tid == 0) SvAcc[p] = 0.0f;   // stale slot: last read this dir1
        if (rc == 0)
            *reinterpret_cast<unsigned*>(&v_bf[c0]) =
                (unsigned)f2bf(v0) | ((unsigned)f2bf(v1) << 16);
        ubd = ubd_new;
        vbd = vbd_new;
        __syncthreads();   // barrier B: v + SvAcc[p^1] published
    }

    // ---- publish final u, v in f32 for the epilogue ----
    if (lr == 0) {
        f32x4 uf = {u4[0], u4[1], u4[2], u4[3]};
        *reinterpret_cast<f32x4*>(&u_f[r_a0]) = uf;
    }
    if (rc == 0) {
        v_f[c0]     = v0;
        v_f[c0 + 1] = v1;
    }
    __syncthreads();

    // ================= epilogue =================
    // T = (u*k)*v with identical mul order and identical bf16 K bits on both
    // panels -> bitwise-consistent equality tests for mutual argmax.
    float rm;   // rowmax of this lane's row (dir1 layout)
    {
        const float ur = u_f[myrow];
        float mm = 0.0f;
        #pragma unroll
        for (int t = 0; t < 8; ++t) {
            const f32x4 va = *reinterpret_cast<const f32x4*>(&v_f[32 * t + 8 * lk]);
            const f32x4 vb = *reinterpret_cast<const f32x4*>(&v_f[32 * t + 8 * lk + 4]);
            const float vj[8] = {va[0], va[1], va[2], va[3], vb[0], vb[1], vb[2], vb[3]};
            #pragma unroll
            for (int j = 0; j < 8; ++j) {
                const float tv = ur * bf2f(KA[t][j]) * vj[j];
                mm = fmaxf(mm, tv);
            }
        }
        mm = swz_maxf<SWZ16>(mm);
        mm = fmaxf(mm, __shfl_xor(mm, 32, 64));
        rm = mm;
        if (lk == 0) rm_s[myrow] = mm;
    }
    float cmv0 = 0.0f, cmv1 = 0.0f;   // colmax of lane's 2 cols (dir2 layout)
    {
        const float vc0 = v_f[c0];
        const float vc1 = v_f[c0 + 1];
        #pragma unroll
        for (int g = 0; g < 4; ++g) {
            const u32x4 K0 = *reinterpret_cast<const u32x4*>(myKC0 + g * 256);
            const u32x4 K1 = *reinterpret_cast<const u32x4*>(myKC1 + g * 256);
            const f32x4 ua  = *reinterpret_cast<const f32x4*>(&u_f[32 * rc + 8 * g]);
            const f32x4 ub2 = *reinterpret_cast<const f32x4*>(&u_f[32 * rc + 8 * g + 4]);
            const float uu[8] = {ua[0], ua[1], ua[2], ua[3], ub2[0], ub2[1], ub2[2], ub2[3]};
            #pragma unroll
            for (int s = 0; s < 4; ++s) {
                cmv0 = fmaxf(cmv0, fmaxf((uu[2*s] * bflo(K0[s])) * vc0,
                                         (uu[2*s+1] * bfhi(K0[s])) * vc0));
                cmv1 = fmaxf(cmv1, fmaxf((uu[2*s] * bflo(K1[s])) * vc1,
                                         (uu[2*s+1] * bfhi(K1[s])) * vc1));
            }
        }
        cmv0 = dpp_maxf<QX1>(cmv0); cmv0 = dpp_maxf<QX2>(cmv0); cmv0 = swz_maxf<SWZ4>(cmv0);
        cmv1 = dpp_maxf<QX1>(cmv1); cmv1 = dpp_maxf<QX2>(cmv1); cmv1 = swz_maxf<SWZ4>(cmv1);
        if (rc == 0) {
            cm_s[c0]     = cmv0;
            cm_s[c0 + 1] = cmv1;
        }
    }
    __syncthreads();   // rm_s / cm_s published

    float* Ot = out_t + (size_t)b * L_FLAT;
    float* Oa = out_a + (size_t)b * L_FLAT;
    const int stride = nd + 1;

    // births row (dir2 layout: col-has + write) + corner
    {
        const float vc[2]  = {v_f[c0], v_f[c0 + 1]};
        const float cmx[2] = {cmv0, cmv1};
        int has0 = 0, has1 = 0;
        #pragma unroll
        for (int g = 0; g < 4; ++g) {
            const u32x4 K0 = *reinterpret_cast<const u32x4*>(myKC0 + g * 256);
            const u32x4 K1 = *reinterpret_cast<const u32x4*>(myKC1 + g * 256);
            const f32x4 ua  = *reinterpret_cast<const f32x4*>(&u_f[32 * rc + 8 * g]);
            const f32x4 ub2 = *reinterpret_cast<const f32x4*>(&u_f[32 * rc + 8 * g + 4]);
            const f32x4 ra  = *reinterpret_cast<const f32x4*>(&rm_s[32 * rc + 8 * g]);
            const f32x4 rb2 = *reinterpret_cast<const f32x4*>(&rm_s[32 * rc + 8 * g + 4]);
            const float uu[8] = {ua[0], ua[1], ua[2], ua[3], ub2[0], ub2[1], ub2[2], ub2[3]};
            const float rr[8] = {ra[0], ra[1], ra[2], ra[3], rb2[0], rb2[1], rb2[2], rb2[3]};
            #pragma unroll
            for (int s = 0; s < 4; ++s) {
                const int r = 32 * rc + 8 * g + 2 * s;
                const float t00 = (uu[2*s]   * bflo(K0[s])) * vc[0];
                const float t01 = (uu[2*s+1] * bfhi(K0[s])) * vc[0];
                const float t10 = (uu[2*s]   * bflo(K1[s])) * vc[1];
                const float t11 = (uu[2*s+1] * bfhi(K1[s])) * vc[1];
                if ((r     < nt) && (c0     < nd) && t00 == rr[2*s]   && t00 == cmx[0]) has0 = 1;
                if ((r + 1 < nt) && (c0     < nd) && t01 == rr[2*s+1] && t01 == cmx[0]) has0 = 1;
                if ((r     < nt) && (c0 + 1 < nd) && t10 == rr[2*s]   && t10 == cmx[1]) has1 = 1;
                if ((r + 1 < nt) && (c0 + 1 < nd) && t11 == rr[2*s+1] && t11 == cmx[1]) has1 = 1;
            }
        }
        has0 = dpp_ori<QX1>(has0); has0 = dpp_ori<QX2>(has0); has0 = swz_ori<SWZ4>(has0);
        has1 = dpp_ori<QX1>(has1); has1 = dpp_ori<QX2>(has1); has1 = swz_ori<SWZ4>(has1);
        if (rc == 0) {
            if (c0 < nd) {
                const int kk = nt * stride + c0;
                Ot[kk] = ubd * vc[0];
                Oa[kk] = has0 ? 0.0f : 1.0f;
            }
            if (c0 + 1 < nd) {
                const int kk = nt * stride + c0 + 1;
                Ot[kk] = ubd * vc[1];
                Oa[kk] = has1 ? 0.0f : 1.0f;
            }
        }
    }
    if (tid == 0) {
        const int kk = nt * stride + nd;
        Ot[kk] = ubd * vbd;
        Oa[kk] = 0.0f;
    }

    // interior + deaths (dir1 layout, 16B-packed stores per 4-col group)
    {
        const float ur = u_f[myrow];
        const bool rv = (myrow < nt);
        int has = 0;
        #pragma unroll
        for (int t = 0; t < 8; ++t) {
            const int cb = 32 * t + 8 * lk;
            const f32x4 va  = *reinterpret_cast<const f32x4*>(&v_f[cb]);
            const f32x4 vb  = *reinterpret_cast<const f32x4*>(&v_f[cb + 4]);
            const f32x4 ca  = *reinterpret_cast<const f32x4*>(&cm_s[cb]);
            const f32x4 cb4 = *reinterpret_cast<const f32x4*>(&cm_s[cb + 4]);
            float tvs[8];
            float abs_[8];
            #pragma unroll
            for (int j = 0; j < 4; ++j) {
                const float tv = ur * bf2f(KA[t][j]) * va[j];
                const bool bit = rv && ((cb + j) < nd) && (tv == rm) && (tv == ca[j]);
                tvs[j] = tv; abs_[j] = bit ? 1.0f : 0.0f;
                has |= bit ? 1 : 0;
            }
            #pragma unroll
            for (int j = 0; j < 4; ++j) {
                const float tv = ur * bf2f(KA[t][4 + j]) * vb[j];
                const bool bit = rv && ((cb + 4 + j) < nd) && (tv == rm) && (tv == cb4[j]);
                tvs[4 + j] = tv; abs_[4 + j] = bit ? 1.0f : 0.0f;
                has |= bit ? 1 : 0;
            }
            if (rv) {
                float* OtR = Ot + (size_t)myrow * stride;
                float* OaR = Oa + (size_t)myrow * stride;
                #pragma unroll
                for (int g = 0; g < 2; ++g) {
                    const int cc0 = cb + 4 * g;
                    if (cc0 + 3 < nd) {
                        F4 ot = {tvs[4*g], tvs[4*g+1], tvs[4*g+2], tvs[4*g+3]};
                        F4 oa = {abs_[4*g], abs_[4*g+1], abs_[4*g+2], abs_[4*g+3]};
                        *reinterpret_cast<F4*>(OtR + cc0) = ot;
                        *reinterpret_cast<F4*>(OaR + cc0) = oa;
                    } else {
                        #pragma unroll
                        for (int j = 0; j < 4; ++j) {
                            if (cc0 + j < nd) {
                                OtR[cc0 + j] = tvs[4*g + j];
                                OaR[cc0 + j] = abs_[4*g + j];
                            }
                        }
                    }
                }
            }
        }
        has = swz_ori<SWZ16>(has);
        has |= __shfl_xor(has, 32, 64);
        if (lk == 0 && rv) {
            const int kk = myrow * stride + nd;
            Ot[kk] = ur * vbd;
            Oa[kk] = has ? 0.0f : 1.0f;
        }
    }

    // zero-fill padding [length, L_FLAT)
    const int length = (nt + 1) * stride;
    for (int k = length + tid; k < L_FLAT; k += 1024) {
        Ot[k] = 0.0f;
        Oa[k] = 0.0f;
    }
}

extern "C" void kernel_launch(void* const* d_in, const int* in_sizes, int n_in,
                              void* d_out, int out_size, void* d_ws, size_t ws_size,
                              hipStream_t stream)
{
    const float* aff  = (const float*)d_in[0];
    const int*   ndet = (const int*)d_in[1];
    const int*   ntrk = (const int*)d_in[2];
    const int    Bn   = in_sizes[1];
    float* out_t = (float*)d_out;
    float* out_a = out_t + (size_t)Bn * L_FLAT;
    assoc_sinkhorn_kernel<<<dim3(Bn), dim3(1024), 0, stream>>>(aff, ndet, ntrk, out_t, out_a);
}

// Round 10
// 414.047 us; speedup vs baseline: 1.2155x; 1.2155x over previous
//
#include <hip/hip_runtime.h>

// AssociationLayer: masked Sinkhorn (100 iters) + mutual-argmax assignment.
// R15 = R13 (best, 255 us) + K^T panel in AGPRs via explicit accvgpr asm.
//  R14 post-mortem: VALU dir2 regressed (357 us) - fma+unpack cost > LDS
//  saving, plus u-pair reads aliased banks (7.7M conflicts). REVERTED.
//  R13 model survives: 384 ds_read_b128/CU/iter x ~12 cyc ~= measured
//  ~5100 cyc/iter -> LDS-issue bound. 128 of those reads (KTL) re-fetch a
//  LOOP-INVARIANT matrix. At 1024 thr the file splits 64V+64A and the A half
//  holds only accumulators. R15 parks KB (32 dwords/lane) in AGPRs:
//   - prologue: v_accvgpr_write_b32 x4 per frag ("a" constraints) - the
//     explicit placement R11's allocator refused to do on its own;
//   - dir2: v_accvgpr_read_b32 x4 (plain VALU, scoreboarded; these AGPRs
//     are never MFMA destinations -> no MFMA-read hazard exposure) feeding
//     the BUILTIN mfma (compiler keeps handling MFMA hazards).
//  LDS reads/CU/iter: 384 -> 256; KTL's 128 KB of LDS deleted.
//  dir1 (MFMA + KA regs), Su/Sv ping-pong atomics, masks, epilogue: as R13
//  (epilogue col-panel reads via agpr_load; identical bf16 K bits + mul
//  order -> bitwise-consistent mutual argmax). absmax ~1.0 vs thr 4.92.

#define T_MAX   256
#define L_FLAT  (257 * 257)
#define N_ITERS 100
#define LAMBDA_F 10.0f
#define EPS_F    1e-12f

#define ROR1 0x121
#define ROR2 0x122
#define ROR4 0x124
#define ROR8 0x128

typedef short bf8   __attribute__((ext_vector_type(8)));  // 8 bf16 = 4 VGPRs
typedef float f32x4 __attribute__((ext_vector_type(4)));

struct F4 { float a, b, c, d; };     // 16B payload, 4B-aligned packed store
struct agpr4 { int x, y, z, w; };    // one bf8 fragment parked in 4 AGPRs

__device__ __forceinline__ agpr4 agpr_store(bf8 k) {
    const int* kv = reinterpret_cast<const int*>(&k);
    agpr4 r;
    asm("v_accvgpr_write_b32 %0, %4\n\t"
        "v_accvgpr_write_b32 %1, %5\n\t"
        "v_accvgpr_write_b32 %2, %6\n\t"
        "v_accvgpr_write_b32 %3, %7"
        : "=a"(r.x), "=a"(r.y), "=a"(r.z), "=a"(r.w)
        : "v"(kv[0]), "v"(kv[1]), "v"(kv[2]), "v"(kv[3]));
    return r;
}
__device__ __forceinline__ bf8 agpr_load(agpr4 a) {
    int kv[4];
    asm("v_accvgpr_read_b32 %0, %4\n\t"
        "v_accvgpr_read_b32 %1, %5\n\t"
        "v_accvgpr_read_b32 %2, %6\n\t"
        "v_accvgpr_read_b32 %3, %7"
        : "=v"(kv[0]), "=v"(kv[1]), "=v"(kv[2]), "=v"(kv[3])
        : "a"(a.x), "a"(a.y), "a"(a.z), "a"(a.w));
    return *reinterpret_cast<bf8*>(kv);
}

template<int CTRL>
__device__ __forceinline__ float dpp_addf(float x) {
    int t = __builtin_amdgcn_update_dpp(0, __float_as_int(x), CTRL, 0xF, 0xF, true);
    return x + __int_as_float(t);
}
__device__ __forceinline__ float swz16_addf(float x) {
    return x + __int_as_float(__builtin_amdgcn_ds_swizzle(__float_as_int(x), 0x401F));
}
__device__ __forceinline__ float swz16_maxf(float x) {
    return fmaxf(x, __int_as_float(__builtin_amdgcn_ds_swizzle(__float_as_int(x), 0x401F)));
}
__device__ __forceinline__ int swz16_ori(int x) {
    return x | __builtin_amdgcn_ds_swizzle(x, 0x401F);
}
__device__ __forceinline__ float fast_rcp(float x) {
#if __has_builtin(__builtin_amdgcn_rcpf)
    return __builtin_amdgcn_rcpf(x);
#else
    return 1.0f / x;
#endif
}
__device__ __forceinline__ unsigned short f2bf(float x) {   // RNE f32->bf16
    unsigned u = __float_as_uint(x);
    return (unsigned short)((u + 0x7FFFu + ((u >> 16) & 1u)) >> 16);
}
__device__ __forceinline__ float bf2f(short s) {            // exact bf16->f32
    return __uint_as_float(((unsigned)(unsigned short)s) << 16);
}

__global__ __launch_bounds__(1024, 1) void assoc_sinkhorn_kernel(
    const float* __restrict__ aff,
    const int*   __restrict__ ndet,
    const int*   __restrict__ ntrk,
    float*       __restrict__ out_t,
    float*       __restrict__ out_a)
{
    const int b   = blockIdx.x;
    const int nd  = ndet[b];
    const int nt  = ntrk[b];
    const int tid = threadIdx.x;
    const int w   = tid >> 6;     // wave 0..15 -> rows/cols 16w..16w+15
    const int l   = tid & 63;
    const int lr  = l & 15;       // m/n index within 16x16 tile
    const int lk  = l >> 4;       // k-group 0..3

    __shared__ __align__(16) unsigned short u_bf[256];
    __shared__ __align__(16) unsigned short v_bf[256];
    __shared__ __align__(16) float u_f[256];
    __shared__ __align__(16) float v_f[256];
    __shared__ __align__(16) float SuAcc[2];   // ping-pong cross-wave sums
    __shared__ __align__(16) float SvAcc[2];
    __shared__ __align__(16) float rm_s[256];
    __shared__ __align__(16) float cm_s[256];

    const float ndf = (float)nd;
    const float ntf = (float)nt;

    // ---------------- prologue: build bf16 K fragments ----------------
    bf8   KA[8];    // row-panel (A-op, VGPRs): row 16w+lr, cols 32t+8lk+j
    agpr4 KBa[8];   // col-panel (B-op, AGPRs): col 16w+lr, rows 32t+8lk+j
    const float* Ab = aff + (size_t)b * (T_MAX * T_MAX);

    const int myrow = 16 * w + lr;
    const int mycol = 16 * w + lr;

    {
        const bool rv = (myrow < nt);
        const float* rp = Ab + (size_t)myrow * T_MAX;
        #pragma unroll
        for (int t = 0; t < 8; ++t) {
            const int c0 = 32 * t + 8 * lk;
            const float4 x0 = *reinterpret_cast<const float4*>(rp + c0);
            const float4 x1 = *reinterpret_cast<const float4*>(rp + c0 + 4);
            const float e[8] = {x0.x, x0.y, x0.z, x0.w, x1.x, x1.y, x1.z, x1.w};
            bf8 kk;
            #pragma unroll
            for (int j = 0; j < 8; ++j) {
                const float val = (rv && (c0 + j) < nd) ? __expf(LAMBDA_F * e[j]) : 0.0f;
                kk[j] = (short)f2bf(val);
            }
            KA[t] = kk;
        }
    }
    {
        // col-panel: col 16w+lr, rows 32t+8lk+j -> straight into AGPRs
        const bool cv = (mycol < nd);
        #pragma unroll
        for (int t = 0; t < 8; ++t) {
            const int r0 = 32 * t + 8 * lk;
            bf8 kk;
            #pragma unroll
            for (int j = 0; j < 8; ++j) {
                const float x = Ab[(size_t)(r0 + j) * T_MAX + mycol];
                const float val = (cv && (r0 + j) < nt) ? __expf(LAMBDA_F * x) : 0.0f;
                kk[j] = (short)f2bf(val);
            }
            KBa[t] = agpr_store(kk);
        }
    }

    if (tid < 256) v_bf[tid] = (tid < nd) ? f2bf(1.0f) : (unsigned short)0;
    if (tid == 0) {
        SuAcc[0] = 0.0f; SuAcc[1] = 0.0f;
        SvAcc[0] = ndf;  SvAcc[1] = 0.0f;   // initial Sv = nd (v=1 on valid cols)
    }
    __syncthreads();

    float vbd = 1.0f;   // v[nd]
    float ubd = 0.0f;   // u[nt]

    const int r_a0 = 16 * w + 4 * lk;   // base row of this lane's acc quad
    float u4[4] = {0.f, 0.f, 0.f, 0.f};
    float v0 = 0.0f;

    // loop-invariant validity masks (mul instead of cmp+cndmask in loop)
    float rvm[4];
    #pragma unroll
    for (int q = 0; q < 4; ++q) rvm[q] = ((r_a0 + q) < nt) ? 1.0f : 0.0f;
    const float cvm = (mycol < nd) ? 1.0f : 0.0f;

    // ---------------- Sinkhorn iterations ----------------
    for (int it = 0; it < N_ITERS; ++it) {
        const int p = it & 1;
        const float Sv = SvAcc[p];   // broadcast read; consumed below (slack)

        // ---- dir1: p = K @ v (KA regs; VF = broadcast of v) ----
        f32x4 acc = {0.0f, 0.0f, 0.0f, 0.0f};
        #pragma unroll
        for (int t = 0; t < 8; ++t) {
            const bf8 VF = *reinterpret_cast<const bf8*>(&v_bf[32 * t + 8 * lk]);
            acc = __builtin_amdgcn_mfma_f32_16x16x32_bf16(KA[t], VF, acc, 0, 0, 0);
        }

        const float vbdE = vbd + EPS_F;
        #pragma unroll
        for (int q = 0; q < 4; ++q)
            u4[q] = rvm[q] * fast_rcp(acc[q] + vbdE);

        // wave Sigma(u): sum 4 quads, fold lk groups (x16, x32), one atomic
        {
            float su = (u4[0] + u4[1]) + (u4[2] + u4[3]);
            su = swz16_addf(su);
            su += __shfl_xor(su, 32, 64);
            if (l == 0) atomicAdd(&SuAcc[p], su);
        }
        if (tid == 0) SuAcc[p ^ 1] = 0.0f;   // stale slot: last read prev iter

        // publish u as bf16; writers: lr==0 lanes (4 rows each)
        if (lr == 0) {
            const unsigned p01 = (unsigned)f2bf(u4[0]) | ((unsigned)f2bf(u4[1]) << 16);
            const unsigned p23 = (unsigned)f2bf(u4[2]) | ((unsigned)f2bf(u4[3]) << 16);
            *reinterpret_cast<uint2*>(&u_bf[r_a0]) = uint2{p01, p23};
        }
        __syncthreads();   // barrier A: u + SuAcc[p] published

        const float Su = SuAcc[p];   // one broadcast read
        const float ubd_new = ndf * fast_rcp(Sv + vbd + EPS_F);
        const float vbd_new = ntf * fast_rcp(Su + ubd_new + EPS_F);

        // ---- dir2: q = K^T @ u (B-frags from AGPRs; UF broadcast) ----
        f32x4 qa = {0.0f, 0.0f, 0.0f, 0.0f};
        #pragma unroll
        for (int t = 0; t < 8; ++t) {
            const bf8 UF = *reinterpret_cast<const bf8*>(&u_bf[32 * t + 8 * lk]);
            const bf8 kb = agpr_load(KBa[t]);
            qa = __builtin_amdgcn_mfma_f32_16x16x32_bf16(UF, kb, qa, 0, 0, 0);
        }

        const float ubdE = ubd_new + EPS_F;
        v0 = cvm * fast_rcp(qa[0] + ubdE);

        // wave Sigma(v) over its 16 cols (varies over lr): DPP fold + atomic
        {
            float sv = v0;
            sv = dpp_addf<ROR1>(sv);
            sv = dpp_addf<ROR2>(sv);
            sv = dpp_addf<ROR4>(sv);
            sv = dpp_addf<ROR8>(sv);
            if (l == 0) atomicAdd(&SvAcc[p ^ 1], sv);
        }
        if (tid == 0) SvAcc[p] = 0.0f;   // stale slot: last read this dir1
        if (lk == 0) v_bf[mycol] = f2bf(v0);
        ubd = ubd_new;
        vbd = vbd_new;
        __syncthreads();   // barrier B: v + SvAcc[p^1] published
    }

    // ---- publish final u, v in f32 for the epilogue ----
    if (lr == 0) {
        f32x4 uf = {u4[0], u4[1], u4[2], u4[3]};
        *reinterpret_cast<f32x4*>(&u_f[r_a0]) = uf;
    }
    if (lk == 0) v_f[mycol] = v0;
    __syncthreads();

    // ================= epilogue =================
    // T = (u*k)*v with identical mul order on both panels -> bitwise-
    // consistent equality tests for mutual argmax.
    float rm;   // rowmax of this lane's row
    {
        const float ur = u_f[myrow];
        float mm = 0.0f;
        #pragma unroll
        for (int t = 0; t < 8; ++t) {
            const f32x4 va = *reinterpret_cast<const f32x4*>(&v_f[32 * t + 8 * lk]);
            const f32x4 vb = *reinterpret_cast<const f32x4*>(&v_f[32 * t + 8 * lk + 4]);
            const float vj[8] = {va[0], va[1], va[2], va[3], vb[0], vb[1], vb[2], vb[3]};
            #pragma unroll
            for (int j = 0; j < 8; ++j) {
                const float tv = ur * bf2f(KA[t][j]) * vj[j];
                mm = fmaxf(mm, tv);
            }
        }
        mm = swz16_maxf(mm);
        mm = fmaxf(mm, __shfl_xor(mm, 32, 64));
        rm = mm;
        if (lk == 0) rm_s[myrow] = mm;
    }
    float cmv;  // colmax of this lane's col
    {
        const float vc = v_f[mycol];
        float mm = 0.0f;
        #pragma unroll
        for (int t = 0; t < 8; ++t) {
            const int rb = 32 * t + 8 * lk;
            const bf8 kb = agpr_load(KBa[t]);
            const f32x4 ua = *reinterpret_cast<const f32x4*>(&u_f[rb]);
            const f32x4 ub = *reinterpret_cast<const f32x4*>(&u_f[rb + 4]);
            const float uj[8] = {ua[0], ua[1], ua[2], ua[3], ub[0], ub[1], ub[2], ub[3]};
            #pragma unroll
            for (int j = 0; j < 8; ++j) {
                const float tv = uj[j] * bf2f(kb[j]) * vc;
                mm = fmaxf(mm, tv);
            }
        }
        mm = swz16_maxf(mm);
        mm = fmaxf(mm, __shfl_xor(mm, 32, 64));
        cmv = mm;
        if (lk == 0) cm_s[mycol] = mm;
    }
    __syncthreads();   // rm_s / cm_s published

    float* Ot = out_t + (size_t)b * L_FLAT;
    float* Oa = out_a + (size_t)b * L_FLAT;
    const int stride = nd + 1;

    // births row (col-panel: col-has + write) + corner
    {
        const float vc = v_f[mycol];
        const bool cv = (mycol < nd);
        int has = 0;
        #pragma unroll
        for (int t = 0; t < 8; ++t) {
            const int rb = 32 * t + 8 * lk;
            const bf8 kb = agpr_load(KBa[t]);
            const f32x4 ua = *reinterpret_cast<const f32x4*>(&u_f[rb]);
            const f32x4 ub = *reinterpret_cast<const f32x4*>(&u_f[rb + 4]);
            const f32x4 ra = *reinterpret_cast<const f32x4*>(&rm_s[rb]);
            const f32x4 rb4 = *reinterpret_cast<const f32x4*>(&rm_s[rb + 4]);
            const float uj[8] = {ua[0], ua[1], ua[2], ua[3], ub[0], ub[1], ub[2], ub[3]};
            const float rj[8] = {ra[0], ra[1], ra[2], ra[3], rb4[0], rb4[1], rb4[2], rb4[3]};
            #pragma unroll
            for (int j = 0; j < 8; ++j) {
                const int rowj = rb + j;
                const float tv = uj[j] * bf2f(kb[j]) * vc;
                const bool bit = (rowj < nt) && cv && (tv == rj[j]) && (tv == cmv);
                has |= bit ? 1 : 0;
            }
        }
        has = swz16_ori(has);
        has |= __shfl_xor(has, 32, 64);
        if (lk == 0 && cv) {
            const int kk = nt * stride + mycol;
            Ot[kk] = ubd * vc;
            Oa[kk] = has ? 0.0f : 1.0f;
        }
    }
    if (tid == 0) {
        const int kk = nt * stride + nd;
        Ot[kk] = ubd * vbd;
        Oa[kk] = 0.0f;
    }

    // interior + deaths (row-panel, 16B-packed stores per 4-col group)
    {
        const float ur = u_f[myrow];
        const bool rv = (myrow < nt);
        int has = 0;
        #pragma unroll
        for (int t = 0; t < 8; ++t) {
            const int cb = 32 * t + 8 * lk;
            const f32x4 va  = *reinterpret_cast<const f32x4*>(&v_f[cb]);
            const f32x4 vb  = *reinterpret_cast<const f32x4*>(&v_f[cb + 4]);
            const f32x4 ca  = *reinterpret_cast<const f32x4*>(&cm_s[cb]);
            const f32x4 cb4 = *reinterpret_cast<const f32x4*>(&cm_s[cb + 4]);
            float tvs[8];
            float abs_[8];
            #pragma unroll
            for (int j = 0; j < 4; ++j) {
                const float tv = ur * bf2f(KA[t][j]) * va[j];
                const bool bit = rv && ((cb + j) < nd) && (tv == rm) && (tv == ca[j]);
                tvs[j] = tv; abs_[j] = bit ? 1.0f : 0.0f;
                has |= bit ? 1 : 0;
            }
            #pragma unroll
            for (int j = 0; j < 4; ++j) {
                const float tv = ur * bf2f(KA[t][4 + j]) * vb[j];
                const bool bit = rv && ((cb + 4 + j) < nd) && (tv == rm) && (tv == cb4[j]);
                tvs[4 + j] = tv; abs_[4 + j] = bit ? 1.0f : 0.0f;
                has |= bit ? 1 : 0;
            }
            if (rv) {
                float* OtR = Ot + (size_t)myrow * stride;
                float* OaR = Oa + (size_t)myrow * stride;
                #pragma unroll
                for (int g = 0; g < 2; ++g) {
                    const int c0 = cb + 4 * g;
                    if (c0 + 3 < nd) {
                        F4 ot = {tvs[4*g], tvs[4*g+1], tvs[4*g+2], tvs[4*g+3]};
                        F4 oa = {abs_[4*g], abs_[4*g+1], abs_[4*g+2], abs_[4*g+3]};
                        *reinterpret_cast<F4*>(OtR + c0) = ot;
                        *reinterpret_cast<F4*>(OaR + c0) = oa;
                    } else {
                        #pragma unroll
                        for (int j = 0; j < 4; ++j) {
                            if (c0 + j < nd) {
                                OtR[c0 + j] = tvs[4*g + j];
                                OaR[c0 + j] = abs_[4*g + j];
                            }
                        }
                    }
                }
            }
        }
        has = swz16_ori(has);
        has |= __shfl_xor(has, 32, 64);
        if (lk == 0 && rv) {
            const int kk = myrow * stride + nd;
            Ot[kk] = ur * vbd;
            Oa[kk] = has ? 0.0f : 1.0f;
        }
    }

    // zero-fill padding [length, L_FLAT)
    const int length = (nt + 1) * stride;
    for (int k = length + tid; k < L_FLAT; k += 1024) {
        Ot[k] = 0.0f;
        Oa[k] = 0.0f;
    }
}

extern "C" void kernel_launch(void* const* d_in, const int* in_sizes, int n_in,
                              void* d_out, int out_size, void* d_ws, size_t ws_size,
                              hipStream_t stream)
{
    const float* aff  = (const float*)d_in[0];
    const int*   ndet = (const int*)d_in[1];
    const int*   ntrk = (const int*)d_in[2];
    const int    Bn   = in_sizes[1];
    float* out_t = (float*)d_out;
    float* out_a = out_t + (size_t)Bn * L_FLAT;
    assoc_sinkhorn_kernel<<<dim3(Bn), dim3(1024), 0, stream>>>(aff, ndet, ntrk, out_t, out_a);
}